// Round 20
// baseline (89.164 us; speedup 1.0000x reference)
//
#include <hip/hip_runtime.h>
#include <math.h>

#define B_   16
#define C1_  128
#define C2_  128
#define H_   64
#define W_   64
#define HW_  4096
#define NCH_ 27

typedef __attribute__((ext_vector_type(8))) short  bf16x8;
typedef __attribute__((ext_vector_type(8))) unsigned short u16x8;
typedef __attribute__((ext_vector_type(4))) float  f32x4;
typedef __attribute__((ext_vector_type(4))) unsigned int u32x4;

__device__ __forceinline__ unsigned short f2bf(float f) {
  unsigned int u = __builtin_bit_cast(unsigned int, f);
  u += 0x7fff + ((u >> 16) & 1);
  return (unsigned short)(u >> 16);
}
__device__ __forceinline__ float lo16(unsigned int u) {
  return __builtin_bit_cast(float, u << 16);
}
__device__ __forceinline__ float hi16(unsigned int u) {
  return __builtin_bit_cast(float, u & 0xffff0000u);
}

// ---------------------------------------------------------------------------
// Fused prep kernel (verified round 19): xpose | wpack | wobpack by block
// range, concurrent in one launch.
// ---------------------------------------------------------------------------
__global__ __launch_bounds__(256) void prep_k(
    const float* __restrict__ x, unsigned short* __restrict__ xcl,
    const float* __restrict__ wc, unsigned short* __restrict__ wpk,
    const float* __restrict__ w_off, const float* __restrict__ w_mask,
    unsigned short* __restrict__ wob) {
  __shared__ unsigned short tile[128][66];
  int blk = blockIdx.x;
  int t = threadIdx.x;

  if (blk < 1024) {
    int bid = blk;
    int bh = ((bid & 7) << 7) | (bid >> 3);
    int b = bh >> 6, h = bh & 63;
    int wv = t & 63, cq = t >> 6;
    const float* xb = x + ((size_t)b * 128) * HW_ + h * 64;
#pragma unroll
    for (int i = 0; i < 32; ++i) {
      int c = i * 4 + cq;
      tile[c][wv] = f2bf(xb[(size_t)c * HW_ + wv]);
    }
    __syncthreads();
    int w2 = t >> 2, cg = (t & 3) * 32;
    unsigned short* op = xcl + (((size_t)bh) * 64 + w2) * 128 + cg;
#pragma unroll
    for (int i = 0; i < 4; ++i) {
      u16x8 pk;
#pragma unroll
      for (int j = 0; j < 8; ++j) pk[j] = tile[cg + i * 8 + j][w2];
      *reinterpret_cast<u16x8*>(op + i * 8) = pk;
    }
  } else if (blk < 1024 + 576) {
    int idx = (blk - 1024) * 256 + t;
    if (idx >= 9 * 8 * 4 * 64 * 8) return;
    int j  = idx & 7;
    int l  = (idx >> 3) & 63;
    int kb = (idx >> 9) & 3;
    int ot = (idx >> 11) & 7;
    int n  = idx >> 14;
    int oc = ot * 16 + (l & 15);
    int c  = kb * 32 + (l >> 4) * 8 + j;
    wpk[idx] = f2bf(wc[(oc * 128 + c) * 9 + n]);
  } else {
    int idx = (blk - 1024 - 576) * 256 + t;
    if (idx >= 2 * 36 * 64 * 8) return;
    int j = idx & 7;
    int l = (idx >> 3) & 63;
    int rest = idx >> 9;
    int s = rest % 36;
    int nt = rest / 36;
    int ch = nt * 16 + (l & 15);
    int n = s >> 2;
    int c = (s & 3) * 32 + (l >> 4) * 8 + j;
    float v = 0.f;
    if (ch < 18) v = w_off[((ch * 128) + c) * 9 + n];
    else if (ch < 27) v = w_mask[(((ch - 18) * 128) + c) * 9 + n];
    wob[idx] = f2bf(v);
  }
}

// ---------------------------------------------------------------------------
// Kernel E v15: v14 (verified r18/r19) + FUSED offset/mask phase.
// Phase A (new): after xrow staging, each wave computes om for its own row /
// px-quarter with the VERBATIM offmask MFMA math — A-frags from the staged
// swizzled xrow (OOB pixels zeroed via exec-masked load instead of r4's halo
// slots; in-bounds rows h-1..h+1 are always within the staged [h0-2,h0+3]),
// B-frags from global wob as before. Results transposed through the idle
// wlds[1] region (14.3 KB of 32 KB; tap-0 weights occupy wlds[0]; a barrier
// after the omv read fences tap-0's later commit into wlds[1]).
// Deletes offmask_k: its launch, its duplicate xcl staging, om round-trip.
// Main loop byte-identical to v14.
// ---------------------------------------------------------------------------
__device__ __forceinline__ bf16x8 blend4(u16x8 a, u16x8 b, u16x8 c, u16x8 d,
                                         float w0, float w1, float w2, float w3) {
  u32x4 ua = __builtin_bit_cast(u32x4, a);
  u32x4 ub = __builtin_bit_cast(u32x4, b);
  u32x4 uc = __builtin_bit_cast(u32x4, c);
  u32x4 ud = __builtin_bit_cast(u32x4, d);
  u32x4 r;
#pragma unroll
  for (int e = 0; e < 4; ++e) {
    float lo = w0 * lo16(ua[e]) + w1 * lo16(ub[e]) + w2 * lo16(uc[e]) + w3 * lo16(ud[e]);
    float hi = w0 * hi16(ua[e]) + w1 * hi16(ub[e]) + w2 * hi16(uc[e]) + w3 * hi16(ud[e]);
    unsigned ulo = __builtin_bit_cast(unsigned, lo) + 0x8000u;   // RNA round
    unsigned uhi = __builtin_bit_cast(unsigned, hi) + 0x8000u;
    r[e] = __builtin_amdgcn_perm(uhi, ulo, 0x07060302u);
  }
  return __builtin_bit_cast(bf16x8, r);
}

__global__ __launch_bounds__(512, 1) void dcn_k(
    const unsigned short* __restrict__ xcl,
    const unsigned short* __restrict__ wpk,
    const unsigned short* __restrict__ wob,
    const float* __restrict__ b_off, const float* __restrict__ b_mask,
    float* __restrict__ out) {
  __shared__ __attribute__((aligned(16))) unsigned short xrow[6 * 64 * 128];   // 98304 B
  __shared__ __attribute__((aligned(16))) unsigned short wlds[2][16384];       // 65536 B

  int bid = blockIdx.x;                       // 0..511
  int bp = ((bid & 7) << 6) | (bid >> 3);     // XCD-chunked (512 % 8 == 0)
  int b = bp >> 5;
  int h0 = (bp & 31) * 2;
  int t = threadIdx.x;                        // 0..511
  int l = t & 63;
  int w = t >> 6;                             // 0..7
  int r = w >> 2;                             // row within pair
  int q = w & 3;                              // px quarter
  int h = h0 + r;

  const unsigned short* xb = xcl + ((size_t)b * HW_) * 128;
  const char* xbc = reinterpret_cast<const char*>(xb);

  // ---- prologue: stage rows [lo, hi] of xcl into swizzled LDS ----
  int lo = max(0, h0 - 2), hi = min(63, h0 + 3);
  int nrows = hi - lo + 1;                    // 4..6
  {
    const unsigned short* src = xb + ((size_t)lo * 64) * 128;
    int nchunks = nrows * 1024;               // 16B chunks
    for (int c = t; c < nchunks; c += 512) {
      int x = (c >> 4) & 63;
      unsigned dst = ((unsigned)c * 16) ^ (unsigned)((x & 7) << 4);
      *reinterpret_cast<u16x8*>(reinterpret_cast<char*>(xrow) + dst) =
          *reinterpret_cast<const u16x8*>(src + (size_t)c * 8);
    }
  }

  // ---- prologue: stage tap-0 weights into wlds[0] (independent of xrow) ----
  {
    const unsigned short* wsrc = wpk + t * 8;
    u16x8 wreg[4];
#pragma unroll
    for (int i = 0; i < 4; ++i)
      wreg[i] = *reinterpret_cast<const u16x8*>(wsrc + i * 4096);
#pragma unroll
    for (int i = 0; i < 4; ++i)
      *reinterpret_cast<u16x8*>(&wlds[0][0] + t * 8 + i * 4096) = wreg[i];
  }
  __syncthreads();   // xrow + wlds[0] ready

  int px_l   = q * 16 + (l & 15);   // lane's sampling pixel within its row
  int cslice = (l >> 4) * 16;       // lane's 8-ch byte offset within a kb
  const char* xr = reinterpret_cast<const char*>(xrow);

  // ---- phase A: fused offset/mask conv (verbatim offmask MFMA math) ----
  f32x4 oacc0 = (f32x4)0.f, oacc1 = (f32x4)0.f;
#pragma unroll
  for (int n = 0; n < 9; ++n) {
    int ky = n / 3, kx = n % 3;
    int row_a = h - 1 + ky;
    int col = px_l + kx - 1;
    bool valid = ((unsigned)row_a < 64u) && ((unsigned)col < 64u);
    int p = (row_a - lo) * 64 + col;
    unsigned sxz = (unsigned)((col & 7) << 4);
#pragma unroll
    for (int cs = 0; cs < 4; ++cs) {
      int s = n * 4 + cs;
      bf16x8 afr = {0, 0, 0, 0, 0, 0, 0, 0};
      if (valid)
        afr = *reinterpret_cast<const bf16x8*>(
            xr + (((unsigned)(p * 256 + cs * 64 + cslice)) ^ sxz));
      bf16x8 bf0 = *reinterpret_cast<const bf16x8*>(wob + ((size_t)(0 * 36 + s) * 64 + l) * 8);
      bf16x8 bf1 = *reinterpret_cast<const bf16x8*>(wob + ((size_t)(1 * 36 + s) * 64 + l) * 8);
      oacc0 = __builtin_amdgcn_mfma_f32_16x16x32_bf16(afr, bf0, oacc0, 0, 0, 0);
      oacc1 = __builtin_amdgcn_mfma_f32_16x16x32_bf16(afr, bf1, oacc1, 0, 0, 0);
    }
  }
  // bias + sigmoid, transpose through om_lds (= wlds[1] region, 14.3 KB)
  float* omld = reinterpret_cast<float*>(&wlds[1][0]);   // [2][64][28] f32
#pragma unroll
  for (int nt = 0; nt < 2; ++nt) {
    int ch = nt * 16 + (l & 15);
    f32x4 v = (nt == 0) ? oacc0 : oacc1;
    if (ch < 27) {
      float bias = (ch < 18) ? b_off[ch] : b_mask[ch - 18];
#pragma unroll
      for (int r4 = 0; r4 < 4; ++r4) {
        float y = v[r4] + bias;
        if (ch >= 18) y = 1.f / (1.f + __expf(-y));
        int pxo = q * 16 + (l >> 4) * 4 + r4;
        omld[(r * 64 + pxo) * 28 + ch] = y;
      }
    }
  }
  __syncthreads();   // om_lds ready

  // ---- read this lane's 27 om values into registers ----
  float omv[9][3];
  {
    const float* base = &omld[(r * 64 + px_l) * 28];
#pragma unroll
    for (int n = 0; n < 9; ++n) {
      omv[n][0] = base[2 * n];
      omv[n][1] = base[2 * n + 1];
      omv[n][2] = base[18 + n];
    }
  }
  __syncthreads();   // all reads of wlds[1] done before tap-0 commits into it

  // ---- main loop (v14 verbatim): 1 barrier/tap, prefetched weights ----
  f32x4 acc[8];
#pragma unroll
  for (int t2 = 0; t2 < 8; ++t2) acc[t2] = (f32x4)0.f;

#pragma unroll
  for (int n = 0; n < 9; ++n) {
    u16x8 wreg[4];
    if (n < 8) {
      const unsigned short* wsrc = wpk + (size_t)(n + 1) * 16384 + t * 8;
#pragma unroll
      for (int i = 0; i < 4; ++i)
        wreg[i] = *reinterpret_cast<const u16x8*>(wsrc + i * 4096);
    }

    float oy = omv[n][0];
    float ox = omv[n][1];
    float m_ = omv[n][2];
    float py  = oy + (float)(h - 1 + n / 3);
    float pxf = ox + (float)(px_l - 1 + n % 3);
    float y0f = floorf(py), x0f = floorf(pxf);
    int y0 = (int)y0f, x0 = (int)x0f;
    float wy1 = py - y0f, wx1 = pxf - x0f;
    float wy0 = 1.f - wy1, wx0 = 1.f - wx1;
    bool vy0 = (unsigned)y0 < 64u, vy1 = (unsigned)(y0 + 1) < 64u;
    bool vx0 = (unsigned)x0 < 64u, vx1 = (unsigned)(x0 + 1) < 64u;
    int y0c = min(max(y0, 0), 63), y1c = min(max(y0 + 1, 0), 63);
    int x0c = min(max(x0, 0), 63), x1c = min(max(x0 + 1, 0), 63);
    float w00 = (vy0 && vx0) ? wy0 * wx0 * m_ : 0.f;
    float w01 = (vy0 && vx1) ? wy0 * wx1 * m_ : 0.f;
    float w10 = (vy1 && vx0) ? wy1 * wx0 * m_ : 0.f;
    float w11 = (vy1 && vx1) ? wy1 * wx1 * m_ : 0.f;

    const unsigned short* wb = &wlds[n & 1][0];
    bool inlds = ((unsigned)(y0c - lo) < (unsigned)nrows) &&
                 ((unsigned)(y1c - lo) < (unsigned)nrows);

    if (__all(inlds)) {
      int p00 = (y0c - lo) * 64 + x0c, p01 = (y0c - lo) * 64 + x1c;
      int p10 = (y1c - lo) * 64 + x0c, p11 = (y1c - lo) * 64 + x1c;
      unsigned s00 = (unsigned)((x0c & 7) << 4), s01 = (unsigned)((x1c & 7) << 4);
#pragma unroll
      for (int kb = 0; kb < 4; ++kb) {
        int cb = kb * 64 + cslice;
        u16x8 c0 = *reinterpret_cast<const u16x8*>(xr + (((unsigned)(p00 * 256 + cb)) ^ s00));
        u16x8 c1 = *reinterpret_cast<const u16x8*>(xr + (((unsigned)(p01 * 256 + cb)) ^ s01));
        u16x8 c2 = *reinterpret_cast<const u16x8*>(xr + (((unsigned)(p10 * 256 + cb)) ^ s00));
        u16x8 c3 = *reinterpret_cast<const u16x8*>(xr + (((unsigned)(p11 * 256 + cb)) ^ s01));
        bf16x8 afr = blend4(c0, c1, c2, c3, w00, w01, w10, w11);
#pragma unroll
        for (int t2 = 0; t2 < 8; ++t2) {
          bf16x8 bfr = *reinterpret_cast<const bf16x8*>(
              wb + ((t2 * 4 + kb) * 64 + l) * 8);
          acc[t2] = __builtin_amdgcn_mfma_f32_16x16x32_bf16(afr, bfr, acc[t2], 0, 0, 0);
        }
      }
    } else {
      int i00 = (y0c * 64 + x0c) * 256, i01 = (y0c * 64 + x1c) * 256;
      int i10 = (y1c * 64 + x0c) * 256, i11 = (y1c * 64 + x1c) * 256;
#pragma unroll
      for (int kb = 0; kb < 4; ++kb) {
        int cb = kb * 64 + cslice;
        u16x8 c0 = *reinterpret_cast<const u16x8*>(xbc + i00 + cb);
        u16x8 c1 = *reinterpret_cast<const u16x8*>(xbc + i01 + cb);
        u16x8 c2 = *reinterpret_cast<const u16x8*>(xbc + i10 + cb);
        u16x8 c3 = *reinterpret_cast<const u16x8*>(xbc + i11 + cb);
        bf16x8 afr = blend4(c0, c1, c2, c3, w00, w01, w10, w11);
#pragma unroll
        for (int t2 = 0; t2 < 8; ++t2) {
          bf16x8 bfr = *reinterpret_cast<const bf16x8*>(
              wb + ((t2 * 4 + kb) * 64 + l) * 8);
          acc[t2] = __builtin_amdgcn_mfma_f32_16x16x32_bf16(afr, bfr, acc[t2], 0, 0, 0);
        }
      }
    }

    if (n < 8) {
      unsigned short* wdst = &wlds[(n + 1) & 1][0];
#pragma unroll
      for (int i = 0; i < 4; ++i)
        *reinterpret_cast<u16x8*>(wdst + t * 8 + i * 4096) = wreg[i];
      __syncthreads();
    }
  }

  // ---- epilogue: direct store (disjoint (row,px) per wave) ----
  int oc_l = l & 15;
  int px0 = q * 16 + (l >> 4) * 4;
#pragma unroll
  for (int t2 = 0; t2 < 8; ++t2) {
    int oc = t2 * 16 + oc_l;
    *reinterpret_cast<f32x4*>(out + ((size_t)b * C2_ + oc) * HW_ + h * 64 + px0) = acc[t2];
  }
}

// ---------------------------------------------------------------------------
extern "C" void kernel_launch(void* const* d_in, const int* in_sizes, int n_in,
                              void* d_out, int out_size, void* d_ws, size_t ws_size,
                              hipStream_t stream) {
  const float* x      = (const float*)d_in[0];
  const float* w_conv = (const float*)d_in[1];
  const float* w_off  = (const float*)d_in[2];
  const float* b_off  = (const float*)d_in[3];
  const float* w_mask = (const float*)d_in[4];
  const float* b_mask = (const float*)d_in[5];
  float* out = (float*)d_out;

  // ws layout: om f32 [16*27*4096, now unused] | wpk u16 [147456] | wob u16
  // [36864] | xcl u16 [16*4096*128]  (offsets kept from r19 for continuity)
  float* om = (float*)d_ws;
  unsigned short* wpk = (unsigned short*)(om + (size_t)B_ * NCH_ * HW_);
  unsigned short* wob = wpk + 147456;
  unsigned short* xcl = wob + 36864;

  hipLaunchKernelGGL(prep_k, dim3(1024 + 576 + 144), dim3(256), 0, stream,
                     x, xcl, w_conv, wpk, w_off, w_mask, wob);
  hipLaunchKernelGGL(dcn_k, dim3(512), dim3(512), 0, stream,
                     xcl, wpk, wob, b_off, b_mask, out);
}

// Round 21
// 83.903 us; speedup vs baseline: 1.0627x; 1.0627x over previous
//
#include <hip/hip_runtime.h>
#include <math.h>

#define B_   16
#define C1_  128
#define C2_  128
#define H_   64
#define W_   64
#define HW_  4096
#define NCH_ 27

typedef __attribute__((ext_vector_type(8))) short  bf16x8;
typedef __attribute__((ext_vector_type(8))) unsigned short u16x8;
typedef __attribute__((ext_vector_type(4))) float  f32x4;
typedef __attribute__((ext_vector_type(4))) unsigned int u32x4;

__device__ __forceinline__ unsigned short f2bf(float f) {
  unsigned int u = __builtin_bit_cast(unsigned int, f);
  u += 0x7fff + ((u >> 16) & 1);
  return (unsigned short)(u >> 16);
}
__device__ __forceinline__ float lo16(unsigned int u) {
  return __builtin_bit_cast(float, u << 16);
}
__device__ __forceinline__ float hi16(unsigned int u) {
  return __builtin_bit_cast(float, u & 0xffff0000u);
}

// ---------------------------------------------------------------------------
// Fused prep kernel (verified round 19): xpose | wpack | wobpack by block
// range, concurrent in one launch.
// ---------------------------------------------------------------------------
__global__ __launch_bounds__(256) void prep_k(
    const float* __restrict__ x, unsigned short* __restrict__ xcl,
    const float* __restrict__ wc, unsigned short* __restrict__ wpk,
    const float* __restrict__ w_off, const float* __restrict__ w_mask,
    unsigned short* __restrict__ wob) {
  __shared__ unsigned short tile[128][66];
  int blk = blockIdx.x;
  int t = threadIdx.x;

  if (blk < 1024) {
    // ---- xpose body (verbatim r4) ----
    int bid = blk;
    int bh = ((bid & 7) << 7) | (bid >> 3);
    int b = bh >> 6, h = bh & 63;
    int wv = t & 63, cq = t >> 6;
    const float* xb = x + ((size_t)b * 128) * HW_ + h * 64;
#pragma unroll
    for (int i = 0; i < 32; ++i) {
      int c = i * 4 + cq;
      tile[c][wv] = f2bf(xb[(size_t)c * HW_ + wv]);
    }
    __syncthreads();
    int w2 = t >> 2, cg = (t & 3) * 32;
    unsigned short* op = xcl + (((size_t)bh) * 64 + w2) * 128 + cg;
#pragma unroll
    for (int i = 0; i < 4; ++i) {
      u16x8 pk;
#pragma unroll
      for (int j = 0; j < 8; ++j) pk[j] = tile[cg + i * 8 + j][w2];
      *reinterpret_cast<u16x8*>(op + i * 8) = pk;
    }
  } else if (blk < 1024 + 576) {
    // ---- wpack body (verbatim r2) ----
    int idx = (blk - 1024) * 256 + t;
    if (idx >= 9 * 8 * 4 * 64 * 8) return;
    int j  = idx & 7;
    int l  = (idx >> 3) & 63;
    int kb = (idx >> 9) & 3;
    int ot = (idx >> 11) & 7;
    int n  = idx >> 14;
    int oc = ot * 16 + (l & 15);
    int c  = kb * 32 + (l >> 4) * 8 + j;
    wpk[idx] = f2bf(wc[(oc * 128 + c) * 9 + n]);
  } else {
    // ---- wobpack body (verbatim r4) ----
    int idx = (blk - 1024 - 576) * 256 + t;
    if (idx >= 2 * 36 * 64 * 8) return;
    int j = idx & 7;
    int l = (idx >> 3) & 63;
    int rest = idx >> 9;
    int s = rest % 36;
    int nt = rest / 36;
    int ch = nt * 16 + (l & 15);
    int n = s >> 2;
    int c = (s & 3) * 32 + (l >> 4) * 8 + j;
    float v = 0.f;
    if (ch < 18) v = w_off[((ch * 128) + c) * 9 + n];
    else if (ch < 27) v = w_mask[(((ch - 18) * 128) + c) * 9 + n];
    wob[idx] = f2bf(v);
  }
}

// ---------------------------------------------------------------------------
// Kernel D: offset+mask conv as MFMA GEMM (verified round 4, unchanged).
// ---------------------------------------------------------------------------
__global__ __launch_bounds__(256) void offmask_k(
    const unsigned short* __restrict__ xcl,
    const unsigned short* __restrict__ wob,
    const float* __restrict__ b_off, const float* __restrict__ b_mask,
    float* __restrict__ om) {
  __shared__ __attribute__((aligned(16))) char xr[3 * 66 * 256];
  int bid = blockIdx.x;
  int bh = ((bid & 7) << 7) | (bid >> 3);
  int b = bh >> 6, h = bh & 63;
  int t = threadIdx.x;
  int l = t & 63, w = t >> 6;

#pragma unroll
  for (int ky = 0; ky < 3; ++ky) {
    int hh = h - 1 + ky;
    bool valid = (unsigned)hh < 64u;
    const unsigned short* src = xcl + (((size_t)b * 64 + (valid ? hh : 0)) * 64) * 128;
#pragma unroll
    for (int i = 0; i < 4; ++i) {
      int m = t + i * 256;
      int px = m >> 4;
      int c2 = (m & 15) * 16;
      unsigned off = (unsigned)((ky * 66 + px + 1) * 256 + c2) ^ (((px + 1) & 7) << 4);
      u16x8 v = {0, 0, 0, 0, 0, 0, 0, 0};
      if (valid) v = *reinterpret_cast<const u16x8*>(src + (size_t)m * 8);
      *reinterpret_cast<u16x8*>(xr + off) = v;
    }
  }
  if (t < 96) {
    int r = t >> 5, rem = t & 31;
    int slot = (rem < 16) ? 0 : 65;
    int c2 = (rem & 15) * 16;
    unsigned off = (unsigned)((r * 66 + slot) * 256 + c2) ^ ((slot & 7) << 4);
    u16x8 z = {0, 0, 0, 0, 0, 0, 0, 0};
    *reinterpret_cast<u16x8*>(xr + off) = z;
  }
  __syncthreads();

  f32x4 acc0 = (f32x4)0.f, acc1 = (f32x4)0.f;
#pragma unroll
  for (int n = 0; n < 9; ++n) {
    int ky = n / 3, kx = n % 3;
    int slot = w * 16 + (l & 15) + kx;
#pragma unroll
    for (int cs = 0; cs < 4; ++cs) {
      int s = n * 4 + cs;
      unsigned aoff = (unsigned)((ky * 66 + slot) * 256 + (l >> 4) * 16 + cs * 64)
                      ^ ((unsigned)(slot & 7) << 4);
      bf16x8 afr = *reinterpret_cast<const bf16x8*>(xr + aoff);
      bf16x8 bf0 = *reinterpret_cast<const bf16x8*>(wob + ((size_t)(0 * 36 + s) * 64 + l) * 8);
      bf16x8 bf1 = *reinterpret_cast<const bf16x8*>(wob + ((size_t)(1 * 36 + s) * 64 + l) * 8);
      acc0 = __builtin_amdgcn_mfma_f32_16x16x32_bf16(afr, bf0, acc0, 0, 0, 0);
      acc1 = __builtin_amdgcn_mfma_f32_16x16x32_bf16(afr, bf1, acc1, 0, 0, 0);
    }
  }

  int pxo = w * 16 + (l >> 4) * 4;
#pragma unroll
  for (int nt = 0; nt < 2; ++nt) {
    int ch = nt * 16 + (l & 15);
    f32x4 v = (nt == 0) ? acc0 : acc1;
    if (ch < 27) {
      float bias = (ch < 18) ? b_off[ch] : b_mask[ch - 18];
#pragma unroll
      for (int r = 0; r < 4; ++r) {
        float y = v[r] + bias;
        if (ch >= 18) y = 1.f / (1.f + __expf(-y));
        v[r] = y;
      }
      *reinterpret_cast<f32x4*>(om + ((size_t)b * NCH_ + ch) * HW_ + h * 64 + pxo) = v;
    }
  }
}

// ---------------------------------------------------------------------------
// Kernel E v14 (verified rounds 18/19, byte-identical): r15 structure +
// double-buffered wlds, 1 barrier/tap, prefetched weight staging.
// ---------------------------------------------------------------------------
__device__ __forceinline__ bf16x8 blend4(u16x8 a, u16x8 b, u16x8 c, u16x8 d,
                                         float w0, float w1, float w2, float w3) {
  u32x4 ua = __builtin_bit_cast(u32x4, a);
  u32x4 ub = __builtin_bit_cast(u32x4, b);
  u32x4 uc = __builtin_bit_cast(u32x4, c);
  u32x4 ud = __builtin_bit_cast(u32x4, d);
  u32x4 r;
#pragma unroll
  for (int e = 0; e < 4; ++e) {
    float lo = w0 * lo16(ua[e]) + w1 * lo16(ub[e]) + w2 * lo16(uc[e]) + w3 * lo16(ud[e]);
    float hi = w0 * hi16(ua[e]) + w1 * hi16(ub[e]) + w2 * hi16(uc[e]) + w3 * hi16(ud[e]);
    unsigned ulo = __builtin_bit_cast(unsigned, lo) + 0x8000u;   // RNA round
    unsigned uhi = __builtin_bit_cast(unsigned, hi) + 0x8000u;
    r[e] = __builtin_amdgcn_perm(uhi, ulo, 0x07060302u);  // {uhi[31:16], ulo[31:16]}
  }
  return __builtin_bit_cast(bf16x8, r);
}

__global__ __launch_bounds__(512, 1) void dcn_k(
    const unsigned short* __restrict__ xcl,
    const unsigned short* __restrict__ wpk,
    const float* __restrict__ om,
    float* __restrict__ out) {
  __shared__ __attribute__((aligned(16))) unsigned short xrow[6 * 64 * 128];   // 98304 B
  __shared__ __attribute__((aligned(16))) unsigned short wlds[2][16384];       // 65536 B

  int bid = blockIdx.x;                       // 0..511
  int bp = ((bid & 7) << 6) | (bid >> 3);     // XCD-chunked (512 % 8 == 0)
  int b = bp >> 5;
  int h0 = (bp & 31) * 2;
  int t = threadIdx.x;                        // 0..511
  int l = t & 63;
  int w = t >> 6;                             // 0..7
  int r = w >> 2;                             // row within pair
  int q = w & 3;                              // px quarter
  int h = h0 + r;

  const unsigned short* xb = xcl + ((size_t)b * HW_) * 128;
  const char* xbc = reinterpret_cast<const char*>(xb);

  // ---- prologue: stage rows [lo, hi] of xcl into swizzled LDS ----
  int lo = max(0, h0 - 2), hi = min(63, h0 + 3);
  int nrows = hi - lo + 1;                    // 4..6
  {
    const unsigned short* src = xb + ((size_t)lo * 64) * 128;
    int nchunks = nrows * 1024;               // 16B chunks
    for (int c = t; c < nchunks; c += 512) {
      int x = (c >> 4) & 63;
      unsigned dst = ((unsigned)c * 16) ^ (unsigned)((x & 7) << 4);
      *reinterpret_cast<u16x8*>(reinterpret_cast<char*>(xrow) + dst) =
          *reinterpret_cast<const u16x8*>(src + (size_t)c * 8);
    }
  }

  int px_l   = q * 16 + (l & 15);   // lane's sampling pixel within its row
  int cslice = (l >> 4) * 16;       // lane's 8-ch byte offset within a kb
  const float* ombr = om + (size_t)b * NCH_ * HW_ + h * 64;

  // ---- hoist: all 27 om values for this lane's pixel into registers ----
  float omv[9][3];
#pragma unroll
  for (int n = 0; n < 9; ++n) {
    omv[n][0] = ombr[(2 * n) * HW_ + px_l];
    omv[n][1] = ombr[(2 * n + 1) * HW_ + px_l];
    omv[n][2] = ombr[(18 + n) * HW_ + px_l];
  }

  // ---- prologue: stage tap-0 weights into wlds[0] ----
  {
    const unsigned short* wsrc = wpk + t * 8;
    u16x8 wreg[4];
#pragma unroll
    for (int i = 0; i < 4; ++i)
      wreg[i] = *reinterpret_cast<const u16x8*>(wsrc + i * 4096);
#pragma unroll
    for (int i = 0; i < 4; ++i)
      *reinterpret_cast<u16x8*>(&wlds[0][0] + t * 8 + i * 4096) = wreg[i];
  }
  __syncthreads();   // xrow + wlds[0] ready

  // ---- main loop: 1 barrier/tap, next-tap weights prefetched early ----
  f32x4 acc[8];
#pragma unroll
  for (int t2 = 0; t2 < 8; ++t2) acc[t2] = (f32x4)0.f;

#pragma unroll
  for (int n = 0; n < 9; ++n) {
    // issue next tap's weight loads FIRST (latency hidden under compute)
    u16x8 wreg[4];
    if (n < 8) {
      const unsigned short* wsrc = wpk + (size_t)(n + 1) * 16384 + t * 8;
#pragma unroll
      for (int i = 0; i < 4; ++i)
        wreg[i] = *reinterpret_cast<const u16x8*>(wsrc + i * 4096);
    }

    // per-lane bilinear coords for this pixel/tap (om from registers)
    float oy = omv[n][0];
    float ox = omv[n][1];
    float m_ = omv[n][2];
    float py  = oy + (float)(h - 1 + n / 3);
    float pxf = ox + (float)(px_l - 1 + n % 3);
    float y0f = floorf(py), x0f = floorf(pxf);
    int y0 = (int)y0f, x0 = (int)x0f;
    float wy1 = py - y0f, wx1 = pxf - x0f;
    float wy0 = 1.f - wy1, wx0 = 1.f - wx1;
    bool vy0 = (unsigned)y0 < 64u, vy1 = (unsigned)(y0 + 1) < 64u;
    bool vx0 = (unsigned)x0 < 64u, vx1 = (unsigned)(x0 + 1) < 64u;
    int y0c = min(max(y0, 0), 63), y1c = min(max(y0 + 1, 0), 63);
    int x0c = min(max(x0, 0), 63), x1c = min(max(x0 + 1, 0), 63);
    float w00 = (vy0 && vx0) ? wy0 * wx0 * m_ : 0.f;
    float w01 = (vy0 && vx1) ? wy0 * wx1 * m_ : 0.f;
    float w10 = (vy1 && vx0) ? wy1 * wx0 * m_ : 0.f;
    float w11 = (vy1 && vx1) ? wy1 * wx1 * m_ : 0.f;

    const unsigned short* wb = &wlds[n & 1][0];
    bool inlds = ((unsigned)(y0c - lo) < (unsigned)nrows) &&
                 ((unsigned)(y1c - lo) < (unsigned)nrows);

    if (__all(inlds)) {
      // fast path: all 4 corners from the LDS row cache
      int p00 = (y0c - lo) * 64 + x0c, p01 = (y0c - lo) * 64 + x1c;
      int p10 = (y1c - lo) * 64 + x0c, p11 = (y1c - lo) * 64 + x1c;
      unsigned s00 = (unsigned)((x0c & 7) << 4), s01 = (unsigned)((x1c & 7) << 4);
      const char* xr = reinterpret_cast<const char*>(xrow);
#pragma unroll
      for (int kb = 0; kb < 4; ++kb) {
        int cb = kb * 64 + cslice;
        u16x8 c0 = *reinterpret_cast<const u16x8*>(xr + (((unsigned)(p00 * 256 + cb)) ^ s00));
        u16x8 c1 = *reinterpret_cast<const u16x8*>(xr + (((unsigned)(p01 * 256 + cb)) ^ s01));
        u16x8 c2 = *reinterpret_cast<const u16x8*>(xr + (((unsigned)(p10 * 256 + cb)) ^ s00));
        u16x8 c3 = *reinterpret_cast<const u16x8*>(xr + (((unsigned)(p11 * 256 + cb)) ^ s01));
        bf16x8 afr = blend4(c0, c1, c2, c3, w00, w01, w10, w11);
#pragma unroll
        for (int t2 = 0; t2 < 8; ++t2) {
          bf16x8 bfr = *reinterpret_cast<const bf16x8*>(
              wb + ((t2 * 4 + kb) * 64 + l) * 8);
          acc[t2] = __builtin_amdgcn_mfma_f32_16x16x32_bf16(afr, bfr, acc[t2], 0, 0, 0);
        }
      }
    } else {
      // slow path (data-independent correctness): global gathers
      int i00 = (y0c * 64 + x0c) * 256, i01 = (y0c * 64 + x1c) * 256;
      int i10 = (y1c * 64 + x0c) * 256, i11 = (y1c * 64 + x1c) * 256;
#pragma unroll
      for (int kb = 0; kb < 4; ++kb) {
        int cb = kb * 64 + cslice;
        u16x8 c0 = *reinterpret_cast<const u16x8*>(xbc + i00 + cb);
        u16x8 c1 = *reinterpret_cast<const u16x8*>(xbc + i01 + cb);
        u16x8 c2 = *reinterpret_cast<const u16x8*>(xbc + i10 + cb);
        u16x8 c3 = *reinterpret_cast<const u16x8*>(xbc + i11 + cb);
        bf16x8 afr = blend4(c0, c1, c2, c3, w00, w01, w10, w11);
#pragma unroll
        for (int t2 = 0; t2 < 8; ++t2) {
          bf16x8 bfr = *reinterpret_cast<const bf16x8*>(
              wb + ((t2 * 4 + kb) * 64 + l) * 8);
          acc[t2] = __builtin_amdgcn_mfma_f32_16x16x32_bf16(afr, bfr, acc[t2], 0, 0, 0);
        }
      }
    }

    // commit next tap's weights to the idle buffer, single barrier
    if (n < 8) {
      unsigned short* wdst = &wlds[(n + 1) & 1][0];
#pragma unroll
      for (int i = 0; i < 4; ++i)
        *reinterpret_cast<u16x8*>(wdst + t * 8 + i * 4096) = wreg[i];
      __syncthreads();
    }
  }

  // ---- epilogue: direct store (disjoint (row,px) per wave) ----
  int oc_l = l & 15;
  int px0 = q * 16 + (l >> 4) * 4;
#pragma unroll
  for (int t2 = 0; t2 < 8; ++t2) {
    int oc = t2 * 16 + oc_l;
    *reinterpret_cast<f32x4*>(out + ((size_t)b * C2_ + oc) * HW_ + h * 64 + px0) = acc[t2];
  }
}

// ---------------------------------------------------------------------------
extern "C" void kernel_launch(void* const* d_in, const int* in_sizes, int n_in,
                              void* d_out, int out_size, void* d_ws, size_t ws_size,
                              hipStream_t stream) {
  const float* x      = (const float*)d_in[0];
  const float* w_conv = (const float*)d_in[1];
  const float* w_off  = (const float*)d_in[2];
  const float* b_off  = (const float*)d_in[3];
  const float* w_mask = (const float*)d_in[4];
  const float* b_mask = (const float*)d_in[5];
  float* out = (float*)d_out;

  // ws layout: om f32 [16*27*4096] | wpk u16 [147456] | wob u16 [36864] | xcl u16 [16*4096*128]
  float* om = (float*)d_ws;
  unsigned short* wpk = (unsigned short*)(om + (size_t)B_ * NCH_ * HW_);
  unsigned short* wob = wpk + 147456;
  unsigned short* xcl = wob + 36864;

  hipLaunchKernelGGL(prep_k, dim3(1024 + 576 + 144), dim3(256), 0, stream,
                     x, xcl, w_conv, wpk, w_off, w_mask, wob);
  hipLaunchKernelGGL(offmask_k, dim3(B_ * H_), dim3(256), 0, stream,
                     xcl, wob, b_off, b_mask, om);
  hipLaunchKernelGGL(dcn_k, dim3(512), dim3(512), 0, stream,
                     xcl, wpk, om, out);
}